// Round 1
// baseline (3877.149 us; speedup 1.0000x reference)
//
#include <hip/hip_runtime.h>
#include <math.h>

// ---------------- configuration ----------------
#define NHEAD 8
#define HID   768
#define DH    96      // HID / NHEAD
#define FFND  3072
#define EOUTD 256
#define BATCH 1024
#define SEQ   64
#define TOK   (BATCH*SEQ)   // 65536

#define EPI_RESID 1
#define EPI_GELU  2
#define EPI_OUTF  4
#define EPI_OUTB  8

typedef __attribute__((ext_vector_type(8))) short short8;   // 8 x bf16 (4 VGPRs)
typedef __attribute__((ext_vector_type(4))) float f32x4;    // MFMA C/D

__device__ __forceinline__ float bf2f(unsigned short u) {
  union { unsigned int i; float f; } c; c.i = ((unsigned int)u) << 16; return c.f;
}
__device__ __forceinline__ unsigned short f2bf(float f) {
  union { float f; unsigned int i; } c; c.f = f;
  unsigned int x = c.i + 0x7fffu + ((c.i >> 16) & 1u);   // RNE
  return (unsigned short)(x >> 16);
}
__device__ __forceinline__ float wsum(float v) {
#pragma unroll
  for (int o = 32; o > 0; o >>= 1) v += __shfl_xor(v, o);
  return v;
}
__device__ __forceinline__ float wmax(float v) {
#pragma unroll
  for (int o = 32; o > 0; o >>= 1) v = fmaxf(v, __shfl_xor(v, o));
  return v;
}

// ---------------- GEMM: C[M,N] = A[M,K] @ W[K,N] (+bias, +resid, gelu) ----------------
// A: bf16 row-major MxK.  Wt: bf16 row-major NxK (pre-transposed weight).
// 128x128 tile, BK=32, 4 waves each computing 4x4 16x16x32-MFMA fragments.
// All of M,N divisible by 128; K divisible by 32 (holds for every instance here).
template<int EPI>
__global__ __launch_bounds__(256) void gemm_k(
    const unsigned short* __restrict__ A, const unsigned short* __restrict__ Wt,
    const float* __restrict__ bias, const float* __restrict__ resid,
    float* __restrict__ outF, unsigned short* __restrict__ outB,
    int M, int N, int K)
{
  __shared__ unsigned short lA[128 * 32];
  __shared__ unsigned short lB[128 * 32];
  const int tid  = threadIdx.x;
  const int m0   = blockIdx.x * 128;
  const int n0   = blockIdx.y * 128;
  const int lane = tid & 63;
  const int wid  = tid >> 6;
  const int wm   = wid & 1, wn = wid >> 1;
  const int m16  = lane & 15, quad = lane >> 4;

  f32x4 zero = {0.0f, 0.0f, 0.0f, 0.0f};
  f32x4 acc[4][4];
#pragma unroll
  for (int i = 0; i < 4; i++)
#pragma unroll
    for (int j = 0; j < 4; j++) acc[i][j] = zero;

  // staging: tile = 512 chunks of 16B; thread covers chunks tid and tid+256
  const int c0 = tid, c1 = tid + 256;
  const long aoff0 = (long)(m0 + (c0 >> 2)) * K + ((c0 & 3) * 8);
  const long aoff1 = (long)(m0 + (c1 >> 2)) * K + ((c1 & 3) * 8);
  const long boff0 = (long)(n0 + (c0 >> 2)) * K + ((c0 & 3) * 8);
  const long boff1 = (long)(n0 + (c1 >> 2)) * K + ((c1 & 3) * 8);

  for (int k0 = 0; k0 < K; k0 += 32) {
    short8 a0 = *(const short8*)(A + aoff0 + k0);
    short8 a1 = *(const short8*)(A + aoff1 + k0);
    short8 b0 = *(const short8*)(Wt + boff0 + k0);
    short8 b1 = *(const short8*)(Wt + boff1 + k0);
    *(short8*)(lA + c0 * 8) = a0;
    *(short8*)(lA + c1 * 8) = a1;
    *(short8*)(lB + c0 * 8) = b0;
    *(short8*)(lB + c1 * 8) = b1;
    __syncthreads();
    short8 af[4], bfr[4];
#pragma unroll
    for (int mi = 0; mi < 4; mi++)
      af[mi] = *(const short8*)(lA + (wm * 64 + mi * 16 + m16) * 32 + quad * 8);
#pragma unroll
    for (int ni = 0; ni < 4; ni++)
      bfr[ni] = *(const short8*)(lB + (wn * 64 + ni * 16 + m16) * 32 + quad * 8);
#pragma unroll
    for (int mi = 0; mi < 4; mi++)
#pragma unroll
      for (int ni = 0; ni < 4; ni++)
        acc[mi][ni] = __builtin_amdgcn_mfma_f32_16x16x32_bf16(af[mi], bfr[ni], acc[mi][ni], 0, 0, 0);
    __syncthreads();
  }

  // epilogue: C/D layout col = lane&15, row = quad*4 + r  [verified m89/m91]
#pragma unroll
  for (int mi = 0; mi < 4; mi++) {
#pragma unroll
    for (int r = 0; r < 4; r++) {
      const int row = m0 + wm * 64 + mi * 16 + quad * 4 + r;
      const long rb = (long)row * N;
#pragma unroll
      for (int ni = 0; ni < 4; ni++) {
        const int col = n0 + wn * 64 + ni * 16 + m16;
        float v = acc[mi][ni][r] + bias[col];
        if (EPI & EPI_RESID) v += resid[rb + col];
        if (EPI & EPI_GELU)  v = 0.5f * v * (1.0f + erff(v * 0.70710678118654752f));
        if (EPI & EPI_OUTF)  outF[rb + col] = v;
        if (EPI & EPI_OUTB)  outB[rb + col] = f2bf(v);
      }
    }
  }
}

// ---------------- Fastformer attention / pooling core ----------------
// One wave per (batch, head). S=64 == wave width; softmaxes are lane-parallel.
// Q,K,V: bf16, layout (b*64+s)*768 + h*96 + d.
template<bool POOL>
__global__ __launch_bounds__(64) void fastattn_k(
    const unsigned short* __restrict__ Q,
    const unsigned short* __restrict__ Kx,
    const unsigned short* __restrict__ V,
    const int* __restrict__ mask,
    unsigned short* __restrict__ attnO,   // !POOL: (T x 768) bf16 = v_w * V
    unsigned short* __restrict__ fused,   // POOL: (1024 x 1536) bf16
    float* __restrict__ qres)             // POOL: (1024 x 768)  f32 (q_global residual)
{
  const int b = blockIdx.x >> 3;
  const int h = blockIdx.x & 7;
  const int lane = threadIdx.x;

  __shared__ unsigned int sQ[64 * 48], sK[64 * 48], sV[64 * 48];
  __shared__ float sw[64];
  __shared__ float qg[96], kg[96], vg[96];

  const unsigned int* Qg = (const unsigned int*)Q;
  const unsigned int* Kg = (const unsigned int*)Kx;
  const unsigned int* Vg = (const unsigned int*)V;
  for (int i = lane; i < 64 * 48; i += 64) {
    const int s = i / 48, du = i % 48;
    const long g = (long)(b * 64 + s) * 384 + h * 48 + du;
    sQ[i] = Qg[g]; sK[i] = Kg[g]; sV[i] = Vg[g];
  }
  const bool mk = (mask[b * 64 + lane] != 0);
  __syncthreads();

  const unsigned short* q16 = (const unsigned short*)sQ;
  const unsigned short* k16 = (const unsigned short*)sK;
  const unsigned short* v16 = (const unsigned short*)sV;

  // ---- q logits: sum_d Q[s,d] / sqrt(96) ----
  for (int s = 0; s < 64; s++) {
    float v = bf2f(q16[s * 96 + lane]);
    if (lane < 32) v += bf2f(q16[s * 96 + 64 + lane]);
    float t = wsum(v);
    if (lane == 0) sw[s] = t;
  }
  __syncthreads();
  {
    float lg = mk ? (sw[lane] * 0.102062072615966f) : -10000.0f;
    float mx = wmax(lg);
    float e = expf(lg - mx);
    float se = wsum(e);
    __syncthreads();
    sw[lane] = e / se;          // q_w
  }
  __syncthreads();
  // ---- q_global[d] = sum_s q_w[s] Q[s,d] ----
#pragma unroll
  for (int half = 0; half < 2; half++) {
    const int d = lane + half * 64;
    if (d < 96) {
      float a = 0.f;
      for (int s = 0; s < 64; s++) a += sw[s] * bf2f(q16[s * 96 + d]);
      qg[d] = a;
    }
  }
  __syncthreads();
  // ---- k logits: K[s,:] . q_global ----
  {
    const float g0 = qg[lane];
    const float g1 = (lane < 32) ? qg[64 + lane] : 0.f;
    for (int s = 0; s < 64; s++) {
      float v = bf2f(k16[s * 96 + lane]) * g0;
      if (lane < 32) v += bf2f(k16[s * 96 + 64 + lane]) * g1;
      float t = wsum(v);
      if (lane == 0) sw[s] = t;
    }
  }
  __syncthreads();
  {
    float lg = mk ? sw[lane] : -10000.0f;
    float mx = wmax(lg);
    float e = expf(lg - mx);
    float se = wsum(e);
    __syncthreads();
    sw[lane] = e / se;          // k_w
  }
  __syncthreads();
  // ---- k_global[d] = sum_s k_w[s] K[s,d] ----
#pragma unroll
  for (int half = 0; half < 2; half++) {
    const int d = lane + half * 64;
    if (d < 96) {
      float a = 0.f;
      for (int s = 0; s < 64; s++) a += sw[s] * bf2f(k16[s * 96 + d]);
      kg[d] = a;
    }
  }
  __syncthreads();
  // ---- v logits: Q[s,:] . k_global ----
  {
    const float g0 = kg[lane];
    const float g1 = (lane < 32) ? kg[64 + lane] : 0.f;
    for (int s = 0; s < 64; s++) {
      float v = bf2f(q16[s * 96 + lane]) * g0;
      if (lane < 32) v += bf2f(q16[s * 96 + 64 + lane]) * g1;
      float t = wsum(v);
      if (lane == 0) sw[s] = t;
    }
  }
  __syncthreads();
  {
    float lg = mk ? sw[lane] : -10000.0f;
    float mx = wmax(lg);
    float e = expf(lg - mx);
    float se = wsum(e);
    __syncthreads();
    sw[lane] = e / se;          // v_w
  }
  __syncthreads();

  if (!POOL) {
    unsigned int* Og = (unsigned int*)attnO;
    for (int i = lane; i < 64 * 48; i += 64) {
      const int s = i / 48, du = i % 48;
      const unsigned int pv = sV[i];
      const float w = sw[s];
      const unsigned short lo = f2bf(w * bf2f((unsigned short)(pv & 0xffffu)));
      const unsigned short hi = f2bf(w * bf2f((unsigned short)(pv >> 16)));
      Og[(long)(b * 64 + s) * 384 + h * 48 + du] = ((unsigned int)hi << 16) | lo;
    }
  } else {
    // v_global
#pragma unroll
    for (int half = 0; half < 2; half++) {
      const int d = lane + half * 64;
      if (d < 96) {
        float a = 0.f;
        for (int s = 0; s < 64; s++) a += sw[s] * bf2f(v16[s * 96 + d]);
        vg[d] = a;
      }
    }
    __syncthreads();
    // fused[b, i*8 + h] : i<96 -> q_global[i], else v_global[i-96]
    for (int i = lane; i < 192; i += 64) {
      const float val = (i < 96) ? qg[i] : vg[i - 96];
      fused[(long)b * 1536 + i * 8 + h] = f2bf(val);
    }
    for (int i = lane; i < 96; i += 64)
      qres[(long)b * 768 + i * 8 + h] = qg[i];
  }
}

// ---------------- LayerNorms ----------------
__global__ __launch_bounds__(256) void ln768_k(
    const float* __restrict__ x, const float* __restrict__ g, const float* __restrict__ b,
    unsigned short* __restrict__ out)
{
  const int tid = threadIdx.x;
  const long row = blockIdx.x;
  const float* xr = x + row * 768;
  const float v0 = xr[tid], v1 = xr[tid + 256], v2 = xr[tid + 512];
  __shared__ float red[4];
  const int wid = tid >> 6, ln = tid & 63;
  float s = wsum(v0 + v1 + v2);
  if (ln == 0) red[wid] = s;
  __syncthreads();
  const float mean = (red[0] + red[1] + red[2] + red[3]) * (1.0f / 768.0f);
  __syncthreads();
  const float d0 = v0 - mean, d1 = v1 - mean, d2 = v2 - mean;
  float q = wsum(d0 * d0 + d1 * d1 + d2 * d2);
  if (ln == 0) red[wid] = q;
  __syncthreads();
  const float var = (red[0] + red[1] + red[2] + red[3]) * (1.0f / 768.0f);
  const float rs = rsqrtf(var + 1e-5f);
  unsigned short* o = out + row * 768;
  o[tid]       = f2bf(d0 * rs * g[tid]       + b[tid]);
  o[tid + 256] = f2bf(d1 * rs * g[tid + 256] + b[tid + 256]);
  o[tid + 512] = f2bf(d2 * rs * g[tid + 512] + b[tid + 512]);
}

// two chained layernorms over 768 (pooling LN then token_norm), bf16 out
__global__ __launch_bounds__(256) void ln2x_k(
    const float* __restrict__ x,
    const float* __restrict__ g1, const float* __restrict__ b1,
    const float* __restrict__ g2, const float* __restrict__ b2,
    unsigned short* __restrict__ out)
{
  const int tid = threadIdx.x;
  const long row = blockIdx.x;
  const float* xr = x + row * 768;
  const float v0 = xr[tid], v1 = xr[tid + 256], v2 = xr[tid + 512];
  __shared__ float red[4];
  const int wid = tid >> 6, ln = tid & 63;
  float s = wsum(v0 + v1 + v2);
  if (ln == 0) red[wid] = s;
  __syncthreads();
  const float mean = (red[0] + red[1] + red[2] + red[3]) * (1.0f / 768.0f);
  __syncthreads();
  const float d0 = v0 - mean, d1 = v1 - mean, d2 = v2 - mean;
  float q = wsum(d0 * d0 + d1 * d1 + d2 * d2);
  if (ln == 0) red[wid] = q;
  __syncthreads();
  const float var = (red[0] + red[1] + red[2] + red[3]) * (1.0f / 768.0f);
  const float rs = rsqrtf(var + 1e-5f);
  const float y0 = d0 * rs * g1[tid]       + b1[tid];
  const float y1 = d1 * rs * g1[tid + 256] + b1[tid + 256];
  const float y2 = d2 * rs * g1[tid + 512] + b1[tid + 512];
  __syncthreads();
  float s2 = wsum(y0 + y1 + y2);
  if (ln == 0) red[wid] = s2;
  __syncthreads();
  const float mean2 = (red[0] + red[1] + red[2] + red[3]) * (1.0f / 768.0f);
  __syncthreads();
  const float e0 = y0 - mean2, e1 = y1 - mean2, e2 = y2 - mean2;
  float q2 = wsum(e0 * e0 + e1 * e1 + e2 * e2);
  if (ln == 0) red[wid] = q2;
  __syncthreads();
  const float var2 = (red[0] + red[1] + red[2] + red[3]) * (1.0f / 768.0f);
  const float rs2 = rsqrtf(var2 + 1e-5f);
  unsigned short* o = out + row * 768;
  o[tid]       = f2bf(e0 * rs2 * g2[tid]       + b2[tid]);
  o[tid + 256] = f2bf(e1 * rs2 * g2[tid + 256] + b2[tid + 256]);
  o[tid + 512] = f2bf(e2 * rs2 * g2[tid + 512] + b2[tid + 512]);
}

// final LN over 256 dims, f32 out
__global__ __launch_bounds__(256) void lnf_k(
    const float* __restrict__ x, const float* __restrict__ g, const float* __restrict__ b,
    float* __restrict__ out)
{
  const int tid = threadIdx.x;
  const long row = blockIdx.x;
  const float v = x[row * 256 + tid];
  __shared__ float red[4];
  const int wid = tid >> 6, ln = tid & 63;
  float s = wsum(v);
  if (ln == 0) red[wid] = s;
  __syncthreads();
  const float mean = (red[0] + red[1] + red[2] + red[3]) * (1.0f / 256.0f);
  __syncthreads();
  const float d = v - mean;
  float q = wsum(d * d);
  if (ln == 0) red[wid] = q;
  __syncthreads();
  const float var = (red[0] + red[1] + red[2] + red[3]) * (1.0f / 256.0f);
  const float rs = rsqrtf(var + 1e-5f);
  out[row * 256 + tid] = d * rs * g[tid] + b[tid];
}

// ---------------- weight transpose + f32->bf16 cast ----------------
// W: K x N f32 row-major  ->  Wt: N x K bf16 row-major
__global__ __launch_bounds__(256) void tcast_k(
    const float* __restrict__ W, unsigned short* __restrict__ Wt, int K, int N)
{
  __shared__ float t[32][33];
  const int tx = threadIdx.x & 31, ty = threadIdx.x >> 5;   // 32 x 8
  const int n0 = blockIdx.x * 32, k0 = blockIdx.y * 32;
#pragma unroll
  for (int j = 0; j < 32; j += 8)
    t[ty + j][tx] = W[(long)(k0 + ty + j) * N + n0 + tx];
  __syncthreads();
#pragma unroll
  for (int j = 0; j < 32; j += 8)
    Wt[(long)(n0 + ty + j) * K + k0 + tx] = f2bf(t[tx][ty + j]);
}

// ---------------- launcher ----------------
extern "C" void kernel_launch(void* const* d_in, const int* in_sizes, int n_in,
                              void* d_out, int out_size, void* d_ws, size_t ws_size,
                              hipStream_t stream)
{
  const float* x    = (const float*)d_in[0];
  const int*   mask = (const int*)d_in[1];
  const float* n1g = (const float*)d_in[2];  const float* n1b = (const float*)d_in[3];
  const float* wq  = (const float*)d_in[4];  const float* bq  = (const float*)d_in[5];
  const float* wk  = (const float*)d_in[6];  const float* bk  = (const float*)d_in[7];
  const float* wv  = (const float*)d_in[8];  const float* bv  = (const float*)d_in[9];
  const float* wo  = (const float*)d_in[10]; const float* bo  = (const float*)d_in[11];
  const float* n2g = (const float*)d_in[12]; const float* n2b = (const float*)d_in[13];
  const float* w1  = (const float*)d_in[14]; const float* b1  = (const float*)d_in[15];
  const float* w2  = (const float*)d_in[16]; const float* b2  = (const float*)d_in[17];
  const float* pwq = (const float*)d_in[18]; const float* pbq = (const float*)d_in[19];
  const float* pwk = (const float*)d_in[20]; const float* pbk = (const float*)d_in[21];
  const float* pwv = (const float*)d_in[22]; const float* pbv = (const float*)d_in[23];
  const float* pwo = (const float*)d_in[24]; const float* pbo = (const float*)d_in[25];
  const float* png = (const float*)d_in[26]; const float* pnb = (const float*)d_in[27];
  const float* tng = (const float*)d_in[28]; const float* tnb = (const float*)d_in[29];
  const float* pjw = (const float*)d_in[30]; const float* pjb = (const float*)d_in[31];
  const float* ong = (const float*)d_in[32]; const float* onb = (const float*)d_in[33];
  float* out = (float*)d_out;

  char* p = (char*)d_ws;
  auto alloc = [&](size_t n) { void* r = (void*)p; p += (n + 255) & ~(size_t)255; return r; };

  // transposed bf16 weights
  unsigned short* wqt   = (unsigned short*)alloc((size_t)HID * HID * 2);
  unsigned short* wkt   = (unsigned short*)alloc((size_t)HID * HID * 2);
  unsigned short* wvt   = (unsigned short*)alloc((size_t)HID * HID * 2);
  unsigned short* wot   = (unsigned short*)alloc((size_t)HID * HID * 2);
  unsigned short* w1t   = (unsigned short*)alloc((size_t)FFND * HID * 2);
  unsigned short* w2t   = (unsigned short*)alloc((size_t)HID * FFND * 2);
  unsigned short* pwqt  = (unsigned short*)alloc((size_t)HID * HID * 2);
  unsigned short* pwkt  = (unsigned short*)alloc((size_t)HID * HID * 2);
  unsigned short* pwvt  = (unsigned short*)alloc((size_t)HID * HID * 2);
  unsigned short* pwot  = (unsigned short*)alloc((size_t)HID * 2 * HID * 2);
  unsigned short* pjwt  = (unsigned short*)alloc((size_t)EOUTD * HID * 2);
  // activations (aliased lifetimes)
  unsigned short* bfA   = (unsigned short*)alloc((size_t)TOK * HID * 2);   // h1 -> h -> x3_bf
  unsigned short* Qb    = (unsigned short*)alloc((size_t)TOK * HID * 2);   // Q -> Qp
  unsigned short* Kb    = (unsigned short*)alloc((size_t)TOK * HID * 2);   // K -> Kp
  unsigned short* Vb    = (unsigned short*)alloc((size_t)TOK * HID * 2);   // V -> Vp
  unsigned short* bfB   = (unsigned short*)alloc((size_t)TOK * HID * 2);   // attn_bf -> ffn-hidden chunk (16384x3072 bf16, same bytes)
  float*          x2    = (float*)alloc((size_t)TOK * HID * 4);
  unsigned short* fusedb= (unsigned short*)alloc((size_t)BATCH * 2 * HID * 2);
  float*          qresb = (float*)alloc((size_t)BATCH * HID * 4);
  float*          preln = (float*)alloc((size_t)BATCH * HID * 4);
  unsigned short* pooledb=(unsigned short*)alloc((size_t)BATCH * HID * 2);
  float*          news  = (float*)alloc((size_t)BATCH * EOUTD * 4);
  (void)ws_size; (void)in_sizes; (void)n_in; (void)out_size;

  // 1. weight transpose+cast
  tcast_k<<<dim3(HID/32,  HID/32),  256, 0, stream>>>(wq,  wqt,  HID,  HID);
  tcast_k<<<dim3(HID/32,  HID/32),  256, 0, stream>>>(wk,  wkt,  HID,  HID);
  tcast_k<<<dim3(HID/32,  HID/32),  256, 0, stream>>>(wv,  wvt,  HID,  HID);
  tcast_k<<<dim3(HID/32,  HID/32),  256, 0, stream>>>(wo,  wot,  HID,  HID);
  tcast_k<<<dim3(FFND/32, HID/32),  256, 0, stream>>>(w1,  w1t,  HID,  FFND);
  tcast_k<<<dim3(HID/32,  FFND/32), 256, 0, stream>>>(w2,  w2t,  FFND, HID);
  tcast_k<<<dim3(HID/32,  HID/32),  256, 0, stream>>>(pwq, pwqt, HID,  HID);
  tcast_k<<<dim3(HID/32,  HID/32),  256, 0, stream>>>(pwk, pwkt, HID,  HID);
  tcast_k<<<dim3(HID/32,  HID/32),  256, 0, stream>>>(pwv, pwvt, HID,  HID);
  tcast_k<<<dim3(HID/32,  (2*HID)/32), 256, 0, stream>>>(pwo, pwot, 2*HID, HID);
  tcast_k<<<dim3(EOUTD/32, HID/32), 256, 0, stream>>>(pjw, pjwt, HID,  EOUTD);

  // 2. LN1: x -> h1 (bf16)
  ln768_k<<<TOK, 256, 0, stream>>>(x, n1g, n1b, bfA);

  // 3. QKV GEMMs (65536x768 @ 768x768, bf16 out)
  gemm_k<EPI_OUTB><<<dim3(TOK/128, HID/128), 256, 0, stream>>>(bfA, wqt, bq, nullptr, nullptr, Qb, TOK, HID, HID);
  gemm_k<EPI_OUTB><<<dim3(TOK/128, HID/128), 256, 0, stream>>>(bfA, wkt, bk, nullptr, nullptr, Kb, TOK, HID, HID);
  gemm_k<EPI_OUTB><<<dim3(TOK/128, HID/128), 256, 0, stream>>>(bfA, wvt, bv, nullptr, nullptr, Vb, TOK, HID, HID);

  // 4. fastformer attention -> attn_bf (v_w * V)
  fastattn_k<false><<<BATCH * NHEAD, 64, 0, stream>>>(Qb, Kb, Vb, mask, bfB, nullptr, nullptr);

  // 5. output proj + residual: x2 = x + attn @ wo + bo  (f32)
  gemm_k<EPI_OUTF | EPI_RESID><<<dim3(TOK/128, HID/128), 256, 0, stream>>>(bfB, wot, bo, x, x2, nullptr, TOK, HID, HID);

  // 6. LN2: x2 -> h (bf16) in bfA (h1 dead)
  ln768_k<<<TOK, 256, 0, stream>>>(x2, n2g, n2b, bfA);

  // 7. FFN in 4 row-chunks of 16384; hidden buffer reuses bfB (attn dead)
  for (int c = 0; c < 4; c++) {
    const size_t ro = (size_t)c * 16384;
    gemm_k<EPI_OUTB | EPI_GELU><<<dim3(16384/128, FFND/128), 256, 0, stream>>>(
        bfA + ro * HID, w1t, b1, nullptr, nullptr, bfB, 16384, FFND, HID);
    gemm_k<EPI_OUTB | EPI_RESID><<<dim3(16384/128, HID/128), 256, 0, stream>>>(
        bfB, w2t, b2, x2 + ro * HID, nullptr, bfA + ro * HID, 16384, HID, FFND);
  }
  // bfA now holds x3 (bf16)

  // 8. pooling QKV GEMMs (reuse Q/K/V buffers)
  gemm_k<EPI_OUTB><<<dim3(TOK/128, HID/128), 256, 0, stream>>>(bfA, pwqt, pbq, nullptr, nullptr, Qb, TOK, HID, HID);
  gemm_k<EPI_OUTB><<<dim3(TOK/128, HID/128), 256, 0, stream>>>(bfA, pwkt, pbk, nullptr, nullptr, Kb, TOK, HID, HID);
  gemm_k<EPI_OUTB><<<dim3(TOK/128, HID/128), 256, 0, stream>>>(bfA, pwvt, pbv, nullptr, nullptr, Vb, TOK, HID, HID);

  // 9. pooling core -> fused (b x 1536 bf16), qres (b x 768 f32)
  fastattn_k<true><<<BATCH * NHEAD, 64, 0, stream>>>(Qb, Kb, Vb, mask, nullptr, fusedb, qresb);

  // 10. pool out proj: preln = fused @ p_wo + p_bo + qres  (1024x1536 @ 1536x768)
  gemm_k<EPI_OUTF | EPI_RESID><<<dim3(BATCH/128, HID/128), 256, 0, stream>>>(
      fusedb, pwot, pbo, qresb, preln, nullptr, BATCH, HID, 2 * HID);

  // 11. LN(p_ng,p_nb) then LN(tn_g,tn_b) -> pooled (bf16)
  ln2x_k<<<BATCH, 256, 0, stream>>>(preln, png, pnb, tng, tnb, pooledb);

  // 12. proj: news = pooled @ proj_w + proj_b  (1024x768 @ 768x256)
  gemm_k<EPI_OUTF><<<dim3(BATCH/128, EOUTD/128), 256, 0, stream>>>(
      pooledb, pjwt, pjb, nullptr, news, nullptr, BATCH, EOUTD, HID);

  // 13. final LN over 256 -> d_out
  lnf_k<<<BATCH, 256, 0, stream>>>(news, ong, onb, out);
}

// Round 2
// 3084.349 us; speedup vs baseline: 1.2570x; 1.2570x over previous
//
#include <hip/hip_runtime.h>
#include <math.h>

// ---------------- configuration ----------------
#define NHEAD 8
#define HID   768
#define DH    96
#define FFND  3072
#define EOUTD 256
#define BATCH 1024
#define SEQ   64
#define TOK   (BATCH*SEQ)   // 65536

#define EPI_RESID 1
#define EPI_GELU  2
#define EPI_OUTF  4
#define EPI_OUTB  8

typedef __attribute__((ext_vector_type(8))) short short8;   // 8 x bf16
typedef __attribute__((ext_vector_type(4))) float f32x4;    // MFMA C/D

#define AS1 __attribute__((address_space(1)))
#define AS3 __attribute__((address_space(3)))

// async global->LDS, 16B per lane. LDS dest must be wave-uniform base; HW puts
// lane i at base + i*16. Integer-detour casts: generic LDS addr low 32 bits ==
// AS(3) offset (apertures are 2^32-aligned); AS(1) is value-identical to flat.
__device__ __forceinline__ void async16(const void* g, void* l) {
  __builtin_amdgcn_global_load_lds(
      (AS1 unsigned int*)(unsigned long long)g,
      (AS3 unsigned int*)(unsigned int)(unsigned long long)l,
      16, 0, 0);
}

__device__ __forceinline__ float bf2f(unsigned short u) {
  union { unsigned int i; float f; } c; c.i = ((unsigned int)u) << 16; return c.f;
}
__device__ __forceinline__ unsigned short f2bf(float f) {
  union { float f; unsigned int i; } c; c.f = f;
  unsigned int x = c.i + 0x7fffu + ((c.i >> 16) & 1u);   // RNE
  return (unsigned short)(x >> 16);
}
__device__ __forceinline__ float wsum(float v) {
#pragma unroll
  for (int o = 32; o > 0; o >>= 1) v += __shfl_xor(v, o);
  return v;
}

// ---------------- GEMM: C[M,N] = A[M,K] @ Wt[N,K]^T (+bias,+resid,gelu) ----------------
// 128x128 tile, BK=32, global_load_lds width-16 staging (m97 structure).
template<int EPI>
__global__ __launch_bounds__(256) void gemm_k(
    const unsigned short* __restrict__ A, const unsigned short* __restrict__ Wt,
    const float* __restrict__ bias, const float* __restrict__ resid,
    float* __restrict__ outF, unsigned short* __restrict__ outB,
    int M, int N, int K)
{
  __shared__ unsigned short lA[128 * 32];
  __shared__ unsigned short lB[128 * 32];
  const int tid  = threadIdx.x;
  const int m0   = blockIdx.x * 128;
  const int n0   = blockIdx.y * 128;
  const int lane = tid & 63;
  const int wid  = tid >> 6;
  const int wm   = wid & 1, wn = wid >> 1;
  const int m16  = lane & 15, quad = lane >> 4;

  f32x4 zero = {0.0f, 0.0f, 0.0f, 0.0f};
  f32x4 acc[4][4];
#pragma unroll
  for (int i = 0; i < 4; i++)
#pragma unroll
    for (int j = 0; j < 4; j++) acc[i][j] = zero;

  // chunk c covers row (c>>2), cols (c&3)*8.. ; thread -> chunks tid, tid+256
  const int c0 = tid, c1 = tid + 256;
  const long aoff0 = (long)(m0 + (c0 >> 2)) * K + ((c0 & 3) * 8);
  const long aoff1 = (long)(m0 + (c1 >> 2)) * K + ((c1 & 3) * 8);
  const long boff0 = (long)(n0 + (c0 >> 2)) * K + ((c0 & 3) * 8);
  const long boff1 = (long)(n0 + (c1 >> 2)) * K + ((c1 & 3) * 8);
  unsigned short* lA0 = lA + (size_t)(wid * 64) * 8;         // wave-uniform bases
  unsigned short* lA1 = lA + (size_t)(256 + wid * 64) * 8;
  unsigned short* lB0 = lB + (size_t)(wid * 64) * 8;
  unsigned short* lB1 = lB + (size_t)(256 + wid * 64) * 8;

  for (int k0 = 0; k0 < K; k0 += 32) {
    async16(A + aoff0 + k0, lA0);
    async16(A + aoff1 + k0, lA1);
    async16(Wt + boff0 + k0, lB0);
    async16(Wt + boff1 + k0, lB1);
    __syncthreads();
    short8 af[4], bfr[4];
#pragma unroll
    for (int mi = 0; mi < 4; mi++)
      af[mi] = *(const short8*)(lA + (wm * 64 + mi * 16 + m16) * 32 + quad * 8);
#pragma unroll
    for (int ni = 0; ni < 4; ni++)
      bfr[ni] = *(const short8*)(lB + (wn * 64 + ni * 16 + m16) * 32 + quad * 8);
#pragma unroll
    for (int mi = 0; mi < 4; mi++)
#pragma unroll
      for (int ni = 0; ni < 4; ni++)
        acc[mi][ni] = __builtin_amdgcn_mfma_f32_16x16x32_bf16(af[mi], bfr[ni], acc[mi][ni], 0, 0, 0);
    __syncthreads();
  }

#pragma unroll
  for (int mi = 0; mi < 4; mi++) {
#pragma unroll
    for (int r = 0; r < 4; r++) {
      const int row = m0 + wm * 64 + mi * 16 + quad * 4 + r;
      const long rb = (long)row * N;
#pragma unroll
      for (int ni = 0; ni < 4; ni++) {
        const int col = n0 + wn * 64 + ni * 16 + m16;
        float v = acc[mi][ni][r] + bias[col];
        if (EPI & EPI_RESID) v += resid[rb + col];
        if (EPI & EPI_GELU)  v = 0.5f * v * (1.0f + erff(v * 0.70710678118654752f));
        if (EPI & EPI_OUTF)  outF[rb + col] = v;
        if (EPI & EPI_OUTB)  outB[rb + col] = f2bf(v);
      }
    }
  }
}

// ---------------- Fastformer attention / pooling: MFMA Gram-matrix version ----------------
// One wave per (b,h); 4 waves/block. Identity: k_logit = (K Q^T) q_w,
// v_logit = (K Q^T)^T k_w. G = K Q^T (64x64) via 16x16x32 MFMA from register
// fragments loaded straight from global. No LDS except tiny v_w broadcast.
template<bool POOL>
__global__ __launch_bounds__(256) void fastattn2_k(
    const unsigned short* __restrict__ Q,
    const unsigned short* __restrict__ Kx,
    const unsigned short* __restrict__ V,
    const int* __restrict__ mask,
    unsigned short* __restrict__ attnO,   // !POOL
    unsigned short* __restrict__ fused,   // POOL: (1024 x 1536) bf16
    float* __restrict__ qres)             // POOL: (1024 x 768)  f32
{
  const int lane = threadIdx.x & 63;
  const int wid  = threadIdx.x >> 6;
  const int gw   = blockIdx.x * 4 + wid;
  const int b = gw >> 3, h = gw & 7;
  const int c = lane & 15, quad = lane >> 4;
  const unsigned short* Qp = Q  + (long)b * 64 * 768 + h * 96;
  const unsigned short* Kp = Kx + (long)b * 64 * 768 + h * 96;
  const unsigned short* Vp = V  + (long)b * 64 * 768 + h * 96;
  const float mval = (mask[b * 64 + lane] != 0) ? 1.0f : 0.0f;

  // ---- G = K Q^T, plus q-logit partials ----
  f32x4 G[4][4];
  f32x4 zero = {0.f, 0.f, 0.f, 0.f};
#pragma unroll
  for (int mi = 0; mi < 4; mi++)
#pragma unroll
    for (int ni = 0; ni < 4; ni++) G[mi][ni] = zero;
  float ql[4] = {0.f, 0.f, 0.f, 0.f};

#pragma unroll
  for (int kc = 0; kc < 3; kc++) {
    const int dcol = kc * 32 + quad * 8;
    short8 afr[4], bfr[4];
#pragma unroll
    for (int mi = 0; mi < 4; mi++)
      afr[mi] = *(const short8*)(Kp + (long)(mi * 16 + c) * 768 + dcol);
#pragma unroll
    for (int ni = 0; ni < 4; ni++)
      bfr[ni] = *(const short8*)(Qp + (long)(ni * 16 + c) * 768 + dcol);
#pragma unroll
    for (int ni = 0; ni < 4; ni++) {
      float t = 0.f;
#pragma unroll
      for (int j = 0; j < 8; j++) t += bf2f((unsigned short)bfr[ni][j]);
      ql[ni] += t;
    }
#pragma unroll
    for (int mi = 0; mi < 4; mi++)
#pragma unroll
      for (int ni = 0; ni < 4; ni++)
        G[mi][ni] = __builtin_amdgcn_mfma_f32_16x16x32_bf16(afr[mi], bfr[ni], G[mi][ni], 0, 0, 0);
  }
  // q logit: reduce partial d-sums across quads (lane holds col s = ni*16+c)
#pragma unroll
  for (int ni = 0; ni < 4; ni++) {
    ql[ni] += __shfl_xor(ql[ni], 16);
    ql[ni] += __shfl_xor(ql[ni], 32);
  }

  // ---- softmax 1 (q_w over cols) ----
  float qw[4];
  {
    float lg[4], mx = -3.4e38f;
#pragma unroll
    for (int ni = 0; ni < 4; ni++) {
      const float mk = __shfl(mval, ni * 16 + c);
      lg[ni] = (mk > 0.5f) ? ql[ni] * 0.102062072615966f : -10000.0f;
      mx = fmaxf(mx, lg[ni]);
    }
#pragma unroll
    for (int o = 1; o <= 8; o <<= 1) mx = fmaxf(mx, __shfl_xor(mx, o));
    float se = 0.f;
#pragma unroll
    for (int ni = 0; ni < 4; ni++) { qw[ni] = expf(lg[ni] - mx); se += qw[ni]; }
#pragma unroll
    for (int o = 1; o <= 8; o <<= 1) se += __shfl_xor(se, o);
    const float inv = 1.0f / se;
#pragma unroll
    for (int ni = 0; ni < 4; ni++) qw[ni] *= inv;
  }

  // ---- k_logit = G q_w  (lane's cols carry its own qw) ----
  float kw[16];   // [mi*4+r], row = mi*16 + quad*4 + r
#pragma unroll
  for (int mi = 0; mi < 4; mi++)
#pragma unroll
    for (int r = 0; r < 4; r++) {
      float a = 0.f;
#pragma unroll
      for (int ni = 0; ni < 4; ni++) a += G[mi][ni][r] * qw[ni];
      kw[mi * 4 + r] = a;
    }
#pragma unroll
  for (int i = 0; i < 16; i++)
#pragma unroll
    for (int o = 1; o <= 8; o <<= 1) kw[i] += __shfl_xor(kw[i], o);

  // ---- softmax 2 (k_w over rows) ----
  {
    float mx2 = -3.4e38f;
#pragma unroll
    for (int i = 0; i < 16; i++) {
      const int mi = i >> 2, r = i & 3;
      const float mk = __shfl(mval, mi * 16 + quad * 4 + r);
      kw[i] = (mk > 0.5f) ? kw[i] : -10000.0f;
      mx2 = fmaxf(mx2, kw[i]);
    }
    mx2 = fmaxf(mx2, __shfl_xor(mx2, 16));
    mx2 = fmaxf(mx2, __shfl_xor(mx2, 32));
    float se2 = 0.f;
#pragma unroll
    for (int i = 0; i < 16; i++) { kw[i] = expf(kw[i] - mx2); se2 += kw[i]; }
    se2 += __shfl_xor(se2, 16);
    se2 += __shfl_xor(se2, 32);
    const float inv = 1.0f / se2;
#pragma unroll
    for (int i = 0; i < 16; i++) kw[i] *= inv;
  }

  // ---- v_logit = G^T k_w ----
  float vw[4];
  {
    float vl[4] = {0.f, 0.f, 0.f, 0.f};
#pragma unroll
    for (int ni = 0; ni < 4; ni++) {
#pragma unroll
      for (int mi = 0; mi < 4; mi++)
#pragma unroll
        for (int r = 0; r < 4; r++) vl[ni] += G[mi][ni][r] * kw[mi * 4 + r];
      vl[ni] += __shfl_xor(vl[ni], 16);
      vl[ni] += __shfl_xor(vl[ni], 32);
    }
    // softmax 3 (v_w over cols)
    float mx = -3.4e38f;
#pragma unroll
    for (int ni = 0; ni < 4; ni++) {
      const float mk = __shfl(mval, ni * 16 + c);
      vl[ni] = (mk > 0.5f) ? vl[ni] : -10000.0f;
      mx = fmaxf(mx, vl[ni]);
    }
#pragma unroll
    for (int o = 1; o <= 8; o <<= 1) mx = fmaxf(mx, __shfl_xor(mx, o));
    float se = 0.f;
#pragma unroll
    for (int ni = 0; ni < 4; ni++) { vw[ni] = expf(vl[ni] - mx); se += vw[ni]; }
#pragma unroll
    for (int o = 1; o <= 8; o <<= 1) se += __shfl_xor(se, o);
    const float inv = 1.0f / se;
#pragma unroll
    for (int ni = 0; ni < 4; ni++) vw[ni] *= inv;
  }

  if (!POOL) {
    // broadcast v_w via tiny LDS, then stream-scale V
    __shared__ float swv[4][64];
    if (quad == 0) {
#pragma unroll
      for (int ni = 0; ni < 4; ni++) swv[wid][ni * 16 + c] = vw[ni];
    }
    __syncthreads();
    unsigned short* Op = attnO + (long)b * 64 * 768 + h * 96;
#pragma unroll
    for (int it = 0; it < 12; it++) {
      const int idx = it * 64 + lane;          // 768 chunks of 8 bf16
      const int s = idx / 12, cw = idx % 12;
      short8 v = *(const short8*)(Vp + (long)s * 768 + cw * 8);
      const float w = swv[wid][s];
      short8 o;
#pragma unroll
      for (int j = 0; j < 8; j++) o[j] = (short)f2bf(w * bf2f((unsigned short)v[j]));
      *(short8*)(Op + (long)s * 768 + cw * 8) = o;
    }
  } else {
    // q_global = Q^T q_w, v_global = V^T v_w via B-fragment re-reads
    float qg[24], vg[24];   // [kc*8 + j], d = kc*32 + quad*8 + j
#pragma unroll
    for (int kc = 0; kc < 3; kc++) {
      const int dcol = kc * 32 + quad * 8;
      short8 fq[4], fv[4];
#pragma unroll
      for (int ni = 0; ni < 4; ni++) {
        fq[ni] = *(const short8*)(Qp + (long)(ni * 16 + c) * 768 + dcol);
        fv[ni] = *(const short8*)(Vp + (long)(ni * 16 + c) * 768 + dcol);
      }
#pragma unroll
      for (int j = 0; j < 8; j++) {
        float aq = 0.f, av = 0.f;
#pragma unroll
        for (int ni = 0; ni < 4; ni++) {
          aq += qw[ni] * bf2f((unsigned short)fq[ni][j]);
          av += vw[ni] * bf2f((unsigned short)fv[ni][j]);
        }
        qg[kc * 8 + j] = aq; vg[kc * 8 + j] = av;
      }
    }
#pragma unroll
    for (int i = 0; i < 24; i++) {
#pragma unroll
      for (int o = 1; o <= 8; o <<= 1) {
        qg[i] += __shfl_xor(qg[i], o);
        vg[i] += __shfl_xor(vg[i], o);
      }
    }
    if (c == 0) {
#pragma unroll
      for (int kc = 0; kc < 3; kc++)
#pragma unroll
        for (int j = 0; j < 8; j++) {
          const int d = kc * 32 + quad * 8 + j;
          const float qv = qg[kc * 8 + j], vv = vg[kc * 8 + j];
          fused[(long)b * 1536 + d * 8 + h]        = f2bf(qv);
          fused[(long)b * 1536 + (96 + d) * 8 + h] = f2bf(vv);
          qres[(long)b * 768 + d * 8 + h] = qv;
        }
    }
  }
}

// ---------------- LayerNorms ----------------
__global__ __launch_bounds__(256) void ln768_k(
    const float* __restrict__ x, const float* __restrict__ g, const float* __restrict__ b,
    unsigned short* __restrict__ out)
{
  const int tid = threadIdx.x;
  const long row = blockIdx.x;
  const float* xr = x + row * 768;
  const float v0 = xr[tid], v1 = xr[tid + 256], v2 = xr[tid + 512];
  __shared__ float red[4];
  const int wid = tid >> 6, ln = tid & 63;
  float s = wsum(v0 + v1 + v2);
  if (ln == 0) red[wid] = s;
  __syncthreads();
  const float mean = (red[0] + red[1] + red[2] + red[3]) * (1.0f / 768.0f);
  __syncthreads();
  const float d0 = v0 - mean, d1 = v1 - mean, d2 = v2 - mean;
  float q = wsum(d0 * d0 + d1 * d1 + d2 * d2);
  if (ln == 0) red[wid] = q;
  __syncthreads();
  const float var = (red[0] + red[1] + red[2] + red[3]) * (1.0f / 768.0f);
  const float rs = rsqrtf(var + 1e-5f);
  unsigned short* o = out + row * 768;
  o[tid]       = f2bf(d0 * rs * g[tid]       + b[tid]);
  o[tid + 256] = f2bf(d1 * rs * g[tid + 256] + b[tid + 256]);
  o[tid + 512] = f2bf(d2 * rs * g[tid + 512] + b[tid + 512]);
}

__global__ __launch_bounds__(256) void ln2x_k(
    const float* __restrict__ x,
    const float* __restrict__ g1, const float* __restrict__ b1,
    const float* __restrict__ g2, const float* __restrict__ b2,
    unsigned short* __restrict__ out)
{
  const int tid = threadIdx.x;
  const long row = blockIdx.x;
  const float* xr = x + row * 768;
  const float v0 = xr[tid], v1 = xr[tid + 256], v2 = xr[tid + 512];
  __shared__ float red[4];
  const int wid = tid >> 6, ln = tid & 63;
  float s = wsum(v0 + v1 + v2);
  if (ln == 0) red[wid] = s;
  __syncthreads();
  const float mean = (red[0] + red[1] + red[2] + red[3]) * (1.0f / 768.0f);
  __syncthreads();
  const float d0 = v0 - mean, d1 = v1 - mean, d2 = v2 - mean;
  float q = wsum(d0 * d0 + d1 * d1 + d2 * d2);
  if (ln == 0) red[wid] = q;
  __syncthreads();
  const float var = (red[0] + red[1] + red[2] + red[3]) * (1.0f / 768.0f);
  const float rs = rsqrtf(var + 1e-5f);
  const float y0 = d0 * rs * g1[tid]       + b1[tid];
  const float y1 = d1 * rs * g1[tid + 256] + b1[tid + 256];
  const float y2 = d2 * rs * g1[tid + 512] + b1[tid + 512];
  __syncthreads();
  float s2 = wsum(y0 + y1 + y2);
  if (ln == 0) red[wid] = s2;
  __syncthreads();
  const float mean2 = (red[0] + red[1] + red[2] + red[3]) * (1.0f / 768.0f);
  __syncthreads();
  const float e0 = y0 - mean2, e1 = y1 - mean2, e2 = y2 - mean2;
  float q2 = wsum(e0 * e0 + e1 * e1 + e2 * e2);
  if (ln == 0) red[wid] = q2;
  __syncthreads();
  const float var2 = (red[0] + red[1] + red[2] + red[3]) * (1.0f / 768.0f);
  const float rs2 = rsqrtf(var2 + 1e-5f);
  unsigned short* o = out + row * 768;
  o[tid]       = f2bf(e0 * rs2 * g2[tid]       + b2[tid]);
  o[tid + 256] = f2bf(e1 * rs2 * g2[tid + 256] + b2[tid + 256]);
  o[tid + 512] = f2bf(e2 * rs2 * g2[tid + 512] + b2[tid + 512]);
}

__global__ __launch_bounds__(256) void lnf_k(
    const float* __restrict__ x, const float* __restrict__ g, const float* __restrict__ b,
    float* __restrict__ out)
{
  const int tid = threadIdx.x;
  const long row = blockIdx.x;
  const float v = x[row * 256 + tid];
  __shared__ float red[4];
  const int wid = tid >> 6, ln = tid & 63;
  float s = wsum(v);
  if (ln == 0) red[wid] = s;
  __syncthreads();
  const float mean = (red[0] + red[1] + red[2] + red[3]) * (1.0f / 256.0f);
  __syncthreads();
  const float d = v - mean;
  float q = wsum(d * d);
  if (ln == 0) red[wid] = q;
  __syncthreads();
  const float var = (red[0] + red[1] + red[2] + red[3]) * (1.0f / 256.0f);
  const float rs = rsqrtf(var + 1e-5f);
  out[row * 256 + tid] = d * rs * g[tid] + b[tid];
}

// ---------------- weight transpose + f32->bf16 cast ----------------
__global__ __launch_bounds__(256) void tcast_k(
    const float* __restrict__ W, unsigned short* __restrict__ Wt, int K, int N)
{
  __shared__ float t[32][33];
  const int tx = threadIdx.x & 31, ty = threadIdx.x >> 5;
  const int n0 = blockIdx.x * 32, k0 = blockIdx.y * 32;
#pragma unroll
  for (int j = 0; j < 32; j += 8)
    t[ty + j][tx] = W[(long)(k0 + ty + j) * N + n0 + tx];
  __syncthreads();
#pragma unroll
  for (int j = 0; j < 32; j += 8)
    Wt[(long)(n0 + ty + j) * K + k0 + tx] = f2bf(t[tx][ty + j]);
}

// ---------------- launcher ----------------
extern "C" void kernel_launch(void* const* d_in, const int* in_sizes, int n_in,
                              void* d_out, int out_size, void* d_ws, size_t ws_size,
                              hipStream_t stream)
{
  const float* x    = (const float*)d_in[0];
  const int*   mask = (const int*)d_in[1];
  const float* n1g = (const float*)d_in[2];  const float* n1b = (const float*)d_in[3];
  const float* wq  = (const float*)d_in[4];  const float* bq  = (const float*)d_in[5];
  const float* wk  = (const float*)d_in[6];  const float* bk  = (const float*)d_in[7];
  const float* wv  = (const float*)d_in[8];  const float* bv  = (const float*)d_in[9];
  const float* wo  = (const float*)d_in[10]; const float* bo  = (const float*)d_in[11];
  const float* n2g = (const float*)d_in[12]; const float* n2b = (const float*)d_in[13];
  const float* w1  = (const float*)d_in[14]; const float* b1  = (const float*)d_in[15];
  const float* w2  = (const float*)d_in[16]; const float* b2  = (const float*)d_in[17];
  const float* pwq = (const float*)d_in[18]; const float* pbq = (const float*)d_in[19];
  const float* pwk = (const float*)d_in[20]; const float* pbk = (const float*)d_in[21];
  const float* pwv = (const float*)d_in[22]; const float* pbv = (const float*)d_in[23];
  const float* pwo = (const float*)d_in[24]; const float* pbo = (const float*)d_in[25];
  const float* png = (const float*)d_in[26]; const float* pnb = (const float*)d_in[27];
  const float* tng = (const float*)d_in[28]; const float* tnb = (const float*)d_in[29];
  const float* pjw = (const float*)d_in[30]; const float* pjb = (const float*)d_in[31];
  const float* ong = (const float*)d_in[32]; const float* onb = (const float*)d_in[33];
  float* out = (float*)d_out;

  char* p = (char*)d_ws;
  auto alloc = [&](size_t n) { void* r = (void*)p; p += (n + 255) & ~(size_t)255; return r; };

  unsigned short* wqt   = (unsigned short*)alloc((size_t)HID * HID * 2);
  unsigned short* wkt   = (unsigned short*)alloc((size_t)HID * HID * 2);
  unsigned short* wvt   = (unsigned short*)alloc((size_t)HID * HID * 2);
  unsigned short* wot   = (unsigned short*)alloc((size_t)HID * HID * 2);
  unsigned short* w1t   = (unsigned short*)alloc((size_t)FFND * HID * 2);
  unsigned short* w2t   = (unsigned short*)alloc((size_t)HID * FFND * 2);
  unsigned short* pwqt  = (unsigned short*)alloc((size_t)HID * HID * 2);
  unsigned short* pwkt  = (unsigned short*)alloc((size_t)HID * HID * 2);
  unsigned short* pwvt  = (unsigned short*)alloc((size_t)HID * HID * 2);
  unsigned short* pwot  = (unsigned short*)alloc((size_t)HID * 2 * HID * 2);
  unsigned short* pjwt  = (unsigned short*)alloc((size_t)EOUTD * HID * 2);
  unsigned short* bfA   = (unsigned short*)alloc((size_t)TOK * HID * 2);
  unsigned short* Qb    = (unsigned short*)alloc((size_t)TOK * HID * 2);
  unsigned short* Kb    = (unsigned short*)alloc((size_t)TOK * HID * 2);
  unsigned short* Vb    = (unsigned short*)alloc((size_t)TOK * HID * 2);
  unsigned short* bfB   = (unsigned short*)alloc((size_t)TOK * HID * 2);
  float*          x2    = (float*)alloc((size_t)TOK * HID * 4);
  unsigned short* fusedb= (unsigned short*)alloc((size_t)BATCH * 2 * HID * 2);
  float*          qresb = (float*)alloc((size_t)BATCH * HID * 4);
  float*          preln = (float*)alloc((size_t)BATCH * HID * 4);
  unsigned short* pooledb=(unsigned short*)alloc((size_t)BATCH * HID * 2);
  float*          news  = (float*)alloc((size_t)BATCH * EOUTD * 4);
  (void)ws_size; (void)in_sizes; (void)n_in; (void)out_size;

  tcast_k<<<dim3(HID/32,  HID/32),  256, 0, stream>>>(wq,  wqt,  HID,  HID);
  tcast_k<<<dim3(HID/32,  HID/32),  256, 0, stream>>>(wk,  wkt,  HID,  HID);
  tcast_k<<<dim3(HID/32,  HID/32),  256, 0, stream>>>(wv,  wvt,  HID,  HID);
  tcast_k<<<dim3(HID/32,  HID/32),  256, 0, stream>>>(wo,  wot,  HID,  HID);
  tcast_k<<<dim3(FFND/32, HID/32),  256, 0, stream>>>(w1,  w1t,  HID,  FFND);
  tcast_k<<<dim3(HID/32,  FFND/32), 256, 0, stream>>>(w2,  w2t,  FFND, HID);
  tcast_k<<<dim3(HID/32,  HID/32),  256, 0, stream>>>(pwq, pwqt, HID,  HID);
  tcast_k<<<dim3(HID/32,  HID/32),  256, 0, stream>>>(pwk, pwkt, HID,  HID);
  tcast_k<<<dim3(HID/32,  HID/32),  256, 0, stream>>>(pwv, pwvt, HID,  HID);
  tcast_k<<<dim3(HID/32,  (2*HID)/32), 256, 0, stream>>>(pwo, pwot, 2*HID, HID);
  tcast_k<<<dim3(EOUTD/32, HID/32), 256, 0, stream>>>(pjw, pjwt, HID,  EOUTD);

  ln768_k<<<TOK, 256, 0, stream>>>(x, n1g, n1b, bfA);

  gemm_k<EPI_OUTB><<<dim3(TOK/128, HID/128), 256, 0, stream>>>(bfA, wqt, bq, nullptr, nullptr, Qb, TOK, HID, HID);
  gemm_k<EPI_OUTB><<<dim3(TOK/128, HID/128), 256, 0, stream>>>(bfA, wkt, bk, nullptr, nullptr, Kb, TOK, HID, HID);
  gemm_k<EPI_OUTB><<<dim3(TOK/128, HID/128), 256, 0, stream>>>(bfA, wvt, bv, nullptr, nullptr, Vb, TOK, HID, HID);

  fastattn2_k<false><<<BATCH * NHEAD / 4, 256, 0, stream>>>(Qb, Kb, Vb, mask, bfB, nullptr, nullptr);

  gemm_k<EPI_OUTF | EPI_RESID><<<dim3(TOK/128, HID/128), 256, 0, stream>>>(bfB, wot, bo, x, x2, nullptr, TOK, HID, HID);

  ln768_k<<<TOK, 256, 0, stream>>>(x2, n2g, n2b, bfA);

  for (int c = 0; c < 4; c++) {
    const size_t ro = (size_t)c * 16384;
    gemm_k<EPI_OUTB | EPI_GELU><<<dim3(16384/128, FFND/128), 256, 0, stream>>>(
        bfA + ro * HID, w1t, b1, nullptr, nullptr, bfB, 16384, FFND, HID);
    gemm_k<EPI_OUTB | EPI_RESID><<<dim3(16384/128, HID/128), 256, 0, stream>>>(
        bfB, w2t, b2, x2 + ro * HID, nullptr, bfA + ro * HID, 16384, HID, FFND);
  }

  gemm_k<EPI_OUTB><<<dim3(TOK/128, HID/128), 256, 0, stream>>>(bfA, pwqt, pbq, nullptr, nullptr, Qb, TOK, HID, HID);
  gemm_k<EPI_OUTB><<<dim3(TOK/128, HID/128), 256, 0, stream>>>(bfA, pwkt, pbk, nullptr, nullptr, Kb, TOK, HID, HID);
  gemm_k<EPI_OUTB><<<dim3(TOK/128, HID/128), 256, 0, stream>>>(bfA, pwvt, pbv, nullptr, nullptr, Vb, TOK, HID, HID);

  fastattn2_k<true><<<BATCH * NHEAD / 4, 256, 0, stream>>>(Qb, Kb, Vb, mask, nullptr, fusedb, qresb);

  gemm_k<EPI_OUTF | EPI_RESID><<<dim3(BATCH/128, HID/128), 256, 0, stream>>>(
      fusedb, pwot, pbo, qresb, preln, nullptr, BATCH, HID, 2 * HID);

  ln2x_k<<<BATCH, 256, 0, stream>>>(preln, png, pnb, tng, tnb, pooledb);

  gemm_k<EPI_OUTF><<<dim3(BATCH/128, EOUTD/128), 256, 0, stream>>>(
      pooledb, pjwt, pjb, nullptr, news, nullptr, BATCH, EOUTD, HID);

  lnf_k<<<BATCH, 256, 0, stream>>>(news, ong, onb, out);
}

// Round 3
// 2688.415 us; speedup vs baseline: 1.4422x; 1.1473x over previous
//
#include <hip/hip_runtime.h>
#include <math.h>

// ---------------- configuration ----------------
#define NHEAD 8
#define HID   768
#define FFND  3072
#define EOUTD 256
#define BATCH 1024
#define TOK   (BATCH*64)   // 65536

#define EPI_RESF  1
#define EPI_RESB  2
#define EPI_GELU  4
#define EPI_OUTF  8
#define EPI_OUTB  16

typedef __attribute__((ext_vector_type(8))) short short8;   // 8 x bf16
typedef __attribute__((ext_vector_type(4))) float f32x4;    // MFMA C/D

#define AS1 __attribute__((address_space(1)))
#define AS3 __attribute__((address_space(3)))

__device__ __forceinline__ void async16(const void* g, void* l) {
  __builtin_amdgcn_global_load_lds(
      (AS1 unsigned int*)(unsigned long long)g,
      (AS3 unsigned int*)(unsigned int)(unsigned long long)l,
      16, 0, 0);
}

__device__ __forceinline__ float bf2f(unsigned short u) {
  union { unsigned int i; float f; } c; c.i = ((unsigned int)u) << 16; return c.f;
}
__device__ __forceinline__ unsigned short f2bf(float f) {
  union { float f; unsigned int i; } c; c.f = f;
  unsigned int x = c.i + 0x7fffu + ((c.i >> 16) & 1u);   // RNE
  return (unsigned short)(x >> 16);
}
__device__ __forceinline__ float wsum(float v) {
#pragma unroll
  for (int o = 32; o > 0; o >>= 1) v += __shfl_xor(v, o);
  return v;
}

// ---------------- GEMM: C[M,N] = A[M,K] @ Wt[N,K]^T (+bias,+resid,gelu) ----------------
// 128x128 tile, BK=64, global_load_lds width-16 staging, XOR-swizzled k-chunks.
// grid = (N/128, M/128) so consecutive blocks share the A-tile (L2 locality).
template<int EPI>
__global__ __launch_bounds__(256) void gemm_k(
    const unsigned short* __restrict__ A, const unsigned short* __restrict__ Wt,
    const float* __restrict__ bias,
    const float* __restrict__ residF, const unsigned short* __restrict__ residB,
    float* __restrict__ outF, unsigned short* __restrict__ outB,
    int M, int N, int K)
{
  __shared__ unsigned short lA[128 * 64];
  __shared__ unsigned short lB[128 * 64];
  const int tid  = threadIdx.x;
  const int n0   = blockIdx.x * 128;
  const int m0   = blockIdx.y * 128;
  const int lane = tid & 63;
  const int wid  = tid >> 6;
  const int wm   = wid & 1, wn = wid >> 1;
  const int m16  = lane & 15, quad = lane >> 4;

  f32x4 zero = {0.0f, 0.0f, 0.0f, 0.0f};
  f32x4 acc[4][4];
#pragma unroll
  for (int i = 0; i < 4; i++)
#pragma unroll
    for (int j = 0; j < 4; j++) acc[i][j] = zero;

  // LDS slot L (0..1023): row = L>>3, kchunk' = L&7 (16B chunks of 8 bf16).
  // Stored global chunk = kchunk' ^ (row&7)  [bank-spread swizzle].
  long aoff[4], boff[4];
#pragma unroll
  for (int j = 0; j < 4; j++) {
    const int L = tid + j * 256;
    const int row = L >> 3;
    const int kc  = (L & 7) ^ (row & 7);
    aoff[j] = (long)(m0 + row) * K + kc * 8;
    boff[j] = (long)(n0 + row) * K + kc * 8;
  }

  for (int k0 = 0; k0 < K; k0 += 64) {
#pragma unroll
    for (int j = 0; j < 4; j++)
      async16(A + aoff[j] + k0, lA + (size_t)(j * 256 + wid * 64) * 8);
#pragma unroll
    for (int j = 0; j < 4; j++)
      async16(Wt + boff[j] + k0, lB + (size_t)(j * 256 + wid * 64) * 8);
    __syncthreads();
#pragma unroll
    for (int s = 0; s < 2; s++) {      // two 32-wide k-steps
      short8 af[4], bfr[4];
#pragma unroll
      for (int mi = 0; mi < 4; mi++) {
        const int row = wm * 64 + mi * 16 + m16;
        const int kc  = (s * 4 + quad) ^ (row & 7);
        af[mi] = *(const short8*)(lA + row * 64 + kc * 8);
      }
#pragma unroll
      for (int ni = 0; ni < 4; ni++) {
        const int row = wn * 64 + ni * 16 + m16;
        const int kc  = (s * 4 + quad) ^ (row & 7);
        bfr[ni] = *(const short8*)(lB + row * 64 + kc * 8);
      }
#pragma unroll
      for (int mi = 0; mi < 4; mi++)
#pragma unroll
        for (int ni = 0; ni < 4; ni++)
          acc[mi][ni] = __builtin_amdgcn_mfma_f32_16x16x32_bf16(af[mi], bfr[ni], acc[mi][ni], 0, 0, 0);
    }
    __syncthreads();
  }

  // epilogue: C/D layout col = lane&15, row = quad*4 + r  [verified m89/m91]
#pragma unroll
  for (int mi = 0; mi < 4; mi++) {
#pragma unroll
    for (int r = 0; r < 4; r++) {
      const int row = m0 + wm * 64 + mi * 16 + quad * 4 + r;
      const long rb = (long)row * N;
#pragma unroll
      for (int ni = 0; ni < 4; ni++) {
        const int col = n0 + wn * 64 + ni * 16 + m16;
        float v = acc[mi][ni][r] + bias[col];
        if (EPI & EPI_RESF) v += residF[rb + col];
        if (EPI & EPI_RESB) v += bf2f(residB[rb + col]);
        if (EPI & EPI_GELU) v = 0.5f * v * (1.0f + erff(v * 0.70710678118654752f));
        if (EPI & EPI_OUTF) outF[rb + col] = v;
        if (EPI & EPI_OUTB) outB[rb + col] = f2bf(v);
      }
    }
  }
}

// ---------------- Fastformer attention / pooling: MFMA Gram-matrix version ----------------
// One wave per (b,h). Inputs Q/K/V with row stride ld (fused QKV layout).
template<bool POOL>
__global__ __launch_bounds__(256) void fastattn2_k(
    const unsigned short* __restrict__ Q,
    const unsigned short* __restrict__ Kx,
    const unsigned short* __restrict__ V,
    int ld,
    const int* __restrict__ mask,
    unsigned short* __restrict__ attnO,   // !POOL: stride 768
    unsigned short* __restrict__ fused,   // POOL: (1024 x 1536) bf16
    float* __restrict__ qres)             // POOL: (1024 x 768)  f32
{
  const int lane = threadIdx.x & 63;
  const int wid  = threadIdx.x >> 6;
  const int gw   = blockIdx.x * 4 + wid;
  const int b = gw >> 3, h = gw & 7;
  const int c = lane & 15, quad = lane >> 4;
  const unsigned short* Qp = Q  + (long)b * 64 * ld + h * 96;
  const unsigned short* Kp = Kx + (long)b * 64 * ld + h * 96;
  const unsigned short* Vp = V  + (long)b * 64 * ld + h * 96;
  const float mval = (mask[b * 64 + lane] != 0) ? 1.0f : 0.0f;

  f32x4 G[4][4];
  f32x4 zero = {0.f, 0.f, 0.f, 0.f};
#pragma unroll
  for (int mi = 0; mi < 4; mi++)
#pragma unroll
    for (int ni = 0; ni < 4; ni++) G[mi][ni] = zero;
  float ql[4] = {0.f, 0.f, 0.f, 0.f};

#pragma unroll
  for (int kc = 0; kc < 3; kc++) {
    const int dcol = kc * 32 + quad * 8;
    short8 afr[4], bfr[4];
#pragma unroll
    for (int mi = 0; mi < 4; mi++)
      afr[mi] = *(const short8*)(Kp + (long)(mi * 16 + c) * ld + dcol);
#pragma unroll
    for (int ni = 0; ni < 4; ni++)
      bfr[ni] = *(const short8*)(Qp + (long)(ni * 16 + c) * ld + dcol);
#pragma unroll
    for (int ni = 0; ni < 4; ni++) {
      float t = 0.f;
#pragma unroll
      for (int j = 0; j < 8; j++) t += bf2f((unsigned short)bfr[ni][j]);
      ql[ni] += t;
    }
#pragma unroll
    for (int mi = 0; mi < 4; mi++)
#pragma unroll
      for (int ni = 0; ni < 4; ni++)
        G[mi][ni] = __builtin_amdgcn_mfma_f32_16x16x32_bf16(afr[mi], bfr[ni], G[mi][ni], 0, 0, 0);
  }
#pragma unroll
  for (int ni = 0; ni < 4; ni++) {
    ql[ni] += __shfl_xor(ql[ni], 16);
    ql[ni] += __shfl_xor(ql[ni], 32);
  }

  // softmax 1 (q_w over cols)
  float qw[4];
  {
    float lg[4], mx = -3.4e38f;
#pragma unroll
    for (int ni = 0; ni < 4; ni++) {
      const float mk = __shfl(mval, ni * 16 + c);
      lg[ni] = (mk > 0.5f) ? ql[ni] * 0.102062072615966f : -10000.0f;
      mx = fmaxf(mx, lg[ni]);
    }
#pragma unroll
    for (int o = 1; o <= 8; o <<= 1) mx = fmaxf(mx, __shfl_xor(mx, o));
    float se = 0.f;
#pragma unroll
    for (int ni = 0; ni < 4; ni++) { qw[ni] = expf(lg[ni] - mx); se += qw[ni]; }
#pragma unroll
    for (int o = 1; o <= 8; o <<= 1) se += __shfl_xor(se, o);
    const float inv = 1.0f / se;
#pragma unroll
    for (int ni = 0; ni < 4; ni++) qw[ni] *= inv;
  }

  // k_logit = G q_w
  float kw[16];
#pragma unroll
  for (int mi = 0; mi < 4; mi++)
#pragma unroll
    for (int r = 0; r < 4; r++) {
      float a = 0.f;
#pragma unroll
      for (int ni = 0; ni < 4; ni++) a += G[mi][ni][r] * qw[ni];
      kw[mi * 4 + r] = a;
    }
#pragma unroll
  for (int i = 0; i < 16; i++)
#pragma unroll
    for (int o = 1; o <= 8; o <<= 1) kw[i] += __shfl_xor(kw[i], o);

  // softmax 2 (k_w over rows)
  {
    float mx2 = -3.4e38f;
#pragma unroll
    for (int i = 0; i < 16; i++) {
      const int mi = i >> 2, r = i & 3;
      const float mk = __shfl(mval, mi * 16 + quad * 4 + r);
      kw[i] = (mk > 0.5f) ? kw[i] : -10000.0f;
      mx2 = fmaxf(mx2, kw[i]);
    }
    mx2 = fmaxf(mx2, __shfl_xor(mx2, 16));
    mx2 = fmaxf(mx2, __shfl_xor(mx2, 32));
    float se2 = 0.f;
#pragma unroll
    for (int i = 0; i < 16; i++) { kw[i] = expf(kw[i] - mx2); se2 += kw[i]; }
    se2 += __shfl_xor(se2, 16);
    se2 += __shfl_xor(se2, 32);
    const float inv = 1.0f / se2;
#pragma unroll
    for (int i = 0; i < 16; i++) kw[i] *= inv;
  }

  // v_logit = G^T k_w ; softmax 3
  float vw[4];
  {
    float vl[4] = {0.f, 0.f, 0.f, 0.f};
#pragma unroll
    for (int ni = 0; ni < 4; ni++) {
#pragma unroll
      for (int mi = 0; mi < 4; mi++)
#pragma unroll
        for (int r = 0; r < 4; r++) vl[ni] += G[mi][ni][r] * kw[mi * 4 + r];
      vl[ni] += __shfl_xor(vl[ni], 16);
      vl[ni] += __shfl_xor(vl[ni], 32);
    }
    float mx = -3.4e38f;
#pragma unroll
    for (int ni = 0; ni < 4; ni++) {
      const float mk = __shfl(mval, ni * 16 + c);
      vl[ni] = (mk > 0.5f) ? vl[ni] : -10000.0f;
      mx = fmaxf(mx, vl[ni]);
    }
#pragma unroll
    for (int o = 1; o <= 8; o <<= 1) mx = fmaxf(mx, __shfl_xor(mx, o));
    float se = 0.f;
#pragma unroll
    for (int ni = 0; ni < 4; ni++) { vw[ni] = expf(vl[ni] - mx); se += vw[ni]; }
#pragma unroll
    for (int o = 1; o <= 8; o <<= 1) se += __shfl_xor(se, o);
    const float inv = 1.0f / se;
#pragma unroll
    for (int ni = 0; ni < 4; ni++) vw[ni] *= inv;
  }

  if (!POOL) {
    __shared__ float swv[4][64];
    if (quad == 0) {
#pragma unroll
      for (int ni = 0; ni < 4; ni++) swv[wid][ni * 16 + c] = vw[ni];
    }
    __syncthreads();
    unsigned short* Op = attnO + (long)b * 64 * 768 + h * 96;
#pragma unroll
    for (int it = 0; it < 12; it++) {
      const int idx = it * 64 + lane;
      const int s = idx / 12, cw = idx % 12;
      short8 v = *(const short8*)(Vp + (long)s * ld + cw * 8);
      const float w = swv[wid][s];
      short8 o;
#pragma unroll
      for (int j = 0; j < 8; j++) o[j] = (short)f2bf(w * bf2f((unsigned short)v[j]));
      *(short8*)(Op + (long)s * 768 + cw * 8) = o;
    }
  } else {
    float qg[24], vg[24];
#pragma unroll
    for (int kc = 0; kc < 3; kc++) {
      const int dcol = kc * 32 + quad * 8;
      short8 fq[4], fv[4];
#pragma unroll
      for (int ni = 0; ni < 4; ni++) {
        fq[ni] = *(const short8*)(Qp + (long)(ni * 16 + c) * ld + dcol);
        fv[ni] = *(const short8*)(Vp + (long)(ni * 16 + c) * ld + dcol);
      }
#pragma unroll
      for (int j = 0; j < 8; j++) {
        float aq = 0.f, av = 0.f;
#pragma unroll
        for (int ni = 0; ni < 4; ni++) {
          aq += qw[ni] * bf2f((unsigned short)fq[ni][j]);
          av += vw[ni] * bf2f((unsigned short)fv[ni][j]);
        }
        qg[kc * 8 + j] = aq; vg[kc * 8 + j] = av;
      }
    }
#pragma unroll
    for (int i = 0; i < 24; i++) {
#pragma unroll
      for (int o = 1; o <= 8; o <<= 1) {
        qg[i] += __shfl_xor(qg[i], o);
        vg[i] += __shfl_xor(vg[i], o);
      }
    }
    if (c == 0) {
#pragma unroll
      for (int kc = 0; kc < 3; kc++)
#pragma unroll
        for (int j = 0; j < 8; j++) {
          const int d = kc * 32 + quad * 8 + j;
          const float qv = qg[kc * 8 + j], vv = vg[kc * 8 + j];
          fused[(long)b * 1536 + d * 8 + h]        = f2bf(qv);
          fused[(long)b * 1536 + (96 + d) * 8 + h] = f2bf(vv);
          qres[(long)b * 768 + d * 8 + h] = qv;
        }
    }
  }
}

// ---------------- LayerNorms ----------------
__global__ __launch_bounds__(256) void ln768_k(
    const float* __restrict__ x, const float* __restrict__ g, const float* __restrict__ b,
    unsigned short* __restrict__ out)
{
  const int tid = threadIdx.x;
  const long row = blockIdx.x;
  const float* xr = x + row * 768;
  const float v0 = xr[tid], v1 = xr[tid + 256], v2 = xr[tid + 512];
  __shared__ float red[4];
  const int wid = tid >> 6, ln = tid & 63;
  float s = wsum(v0 + v1 + v2);
  if (ln == 0) red[wid] = s;
  __syncthreads();
  const float mean = (red[0] + red[1] + red[2] + red[3]) * (1.0f / 768.0f);
  __syncthreads();
  const float d0 = v0 - mean, d1 = v1 - mean, d2 = v2 - mean;
  float q = wsum(d0 * d0 + d1 * d1 + d2 * d2);
  if (ln == 0) red[wid] = q;
  __syncthreads();
  const float var = (red[0] + red[1] + red[2] + red[3]) * (1.0f / 768.0f);
  const float rs = rsqrtf(var + 1e-5f);
  unsigned short* o = out + row * 768;
  o[tid]       = f2bf(d0 * rs * g[tid]       + b[tid]);
  o[tid + 256] = f2bf(d1 * rs * g[tid + 256] + b[tid + 256]);
  o[tid + 512] = f2bf(d2 * rs * g[tid + 512] + b[tid + 512]);
}

// bf16-input variant (LN2 over x2 stored bf16)
__global__ __launch_bounds__(256) void ln768b_k(
    const unsigned short* __restrict__ x, const float* __restrict__ g, const float* __restrict__ b,
    unsigned short* __restrict__ out)
{
  const int tid = threadIdx.x;
  const long row = blockIdx.x;
  const unsigned short* xr = x + row * 768;
  const float v0 = bf2f(xr[tid]), v1 = bf2f(xr[tid + 256]), v2 = bf2f(xr[tid + 512]);
  __shared__ float red[4];
  const int wid = tid >> 6, ln = tid & 63;
  float s = wsum(v0 + v1 + v2);
  if (ln == 0) red[wid] = s;
  __syncthreads();
  const float mean = (red[0] + red[1] + red[2] + red[3]) * (1.0f / 768.0f);
  __syncthreads();
  const float d0 = v0 - mean, d1 = v1 - mean, d2 = v2 - mean;
  float q = wsum(d0 * d0 + d1 * d1 + d2 * d2);
  if (ln == 0) red[wid] = q;
  __syncthreads();
  const float var = (red[0] + red[1] + red[2] + red[3]) * (1.0f / 768.0f);
  const float rs = rsqrtf(var + 1e-5f);
  unsigned short* o = out + row * 768;
  o[tid]       = f2bf(d0 * rs * g[tid]       + b[tid]);
  o[tid + 256] = f2bf(d1 * rs * g[tid + 256] + b[tid + 256]);
  o[tid + 512] = f2bf(d2 * rs * g[tid + 512] + b[tid + 512]);
}

__global__ __launch_bounds__(256) void ln2x_k(
    const float* __restrict__ x,
    const float* __restrict__ g1, const float* __restrict__ b1,
    const float* __restrict__ g2, const float* __restrict__ b2,
    unsigned short* __restrict__ out)
{
  const int tid = threadIdx.x;
  const long row = blockIdx.x;
  const float* xr = x + row * 768;
  const float v0 = xr[tid], v1 = xr[tid + 256], v2 = xr[tid + 512];
  __shared__ float red[4];
  const int wid = tid >> 6, ln = tid & 63;
  float s = wsum(v0 + v1 + v2);
  if (ln == 0) red[wid] = s;
  __syncthreads();
  const float mean = (red[0] + red[1] + red[2] + red[3]) * (1.0f / 768.0f);
  __syncthreads();
  const float d0 = v0 - mean, d1 = v1 - mean, d2 = v2 - mean;
  float q = wsum(d0 * d0 + d1 * d1 + d2 * d2);
  if (ln == 0) red[wid] = q;
  __syncthreads();
  const float var = (red[0] + red[1] + red[2] + red[3]) * (1.0f / 768.0f);
  const float rs = rsqrtf(var + 1e-5f);
  const float y0 = d0 * rs * g1[tid]       + b1[tid];
  const float y1 = d1 * rs * g1[tid + 256] + b1[tid + 256];
  const float y2 = d2 * rs * g1[tid + 512] + b1[tid + 512];
  __syncthreads();
  float s2 = wsum(y0 + y1 + y2);
  if (ln == 0) red[wid] = s2;
  __syncthreads();
  const float mean2 = (red[0] + red[1] + red[2] + red[3]) * (1.0f / 768.0f);
  __syncthreads();
  const float e0 = y0 - mean2, e1 = y1 - mean2, e2 = y2 - mean2;
  float q2 = wsum(e0 * e0 + e1 * e1 + e2 * e2);
  if (ln == 0) red[wid] = q2;
  __syncthreads();
  const float var2 = (red[0] + red[1] + red[2] + red[3]) * (1.0f / 768.0f);
  const float rs2 = rsqrtf(var2 + 1e-5f);
  unsigned short* o = out + row * 768;
  o[tid]       = f2bf(e0 * rs2 * g2[tid]       + b2[tid]);
  o[tid + 256] = f2bf(e1 * rs2 * g2[tid + 256] + b2[tid + 256]);
  o[tid + 512] = f2bf(e2 * rs2 * g2[tid + 512] + b2[tid + 512]);
}

__global__ __launch_bounds__(256) void lnf_k(
    const float* __restrict__ x, const float* __restrict__ g, const float* __restrict__ b,
    float* __restrict__ out)
{
  const int tid = threadIdx.x;
  const long row = blockIdx.x;
  const float v = x[row * 256 + tid];
  __shared__ float red[4];
  const int wid = tid >> 6, ln = tid & 63;
  float s = wsum(v);
  if (ln == 0) red[wid] = s;
  __syncthreads();
  const float mean = (red[0] + red[1] + red[2] + red[3]) * (1.0f / 256.0f);
  __syncthreads();
  const float d = v - mean;
  float q = wsum(d * d);
  if (ln == 0) red[wid] = q;
  __syncthreads();
  const float var = (red[0] + red[1] + red[2] + red[3]) * (1.0f / 256.0f);
  const float rs = rsqrtf(var + 1e-5f);
  out[row * 256 + tid] = d * rs * g[tid] + b[tid];
}

// ---------------- weight transpose + cast, bias concat ----------------
__global__ __launch_bounds__(256) void tcast_k(
    const float* __restrict__ W, unsigned short* __restrict__ Wt, int K, int N)
{
  __shared__ float t[32][33];
  const int tx = threadIdx.x & 31, ty = threadIdx.x >> 5;
  const int n0 = blockIdx.x * 32, k0 = blockIdx.y * 32;
#pragma unroll
  for (int j = 0; j < 32; j += 8)
    t[ty + j][tx] = W[(long)(k0 + ty + j) * N + n0 + tx];
  __syncthreads();
#pragma unroll
  for (int j = 0; j < 32; j += 8)
    Wt[(long)(n0 + ty + j) * K + k0 + tx] = f2bf(t[tx][ty + j]);
}

__global__ __launch_bounds__(256) void cat3_k(
    const float* __restrict__ a, const float* __restrict__ b, const float* __restrict__ c,
    float* __restrict__ dst)
{
  const int i = blockIdx.x * 256 + threadIdx.x;   // grid 9 -> 2304
  dst[i] = (i < 768) ? a[i] : (i < 1536 ? b[i - 768] : c[i - 1536]);
}

// ---------------- launcher ----------------
extern "C" void kernel_launch(void* const* d_in, const int* in_sizes, int n_in,
                              void* d_out, int out_size, void* d_ws, size_t ws_size,
                              hipStream_t stream)
{
  const float* x    = (const float*)d_in[0];
  const int*   mask = (const int*)d_in[1];
  const float* n1g = (const float*)d_in[2];  const float* n1b = (const float*)d_in[3];
  const float* wq  = (const float*)d_in[4];  const float* bq  = (const float*)d_in[5];
  const float* wk  = (const float*)d_in[6];  const float* bk  = (const float*)d_in[7];
  const float* wv  = (const float*)d_in[8];  const float* bv  = (const float*)d_in[9];
  const float* wo  = (const float*)d_in[10]; const float* bo  = (const float*)d_in[11];
  const float* n2g = (const float*)d_in[12]; const float* n2b = (const float*)d_in[13];
  const float* w1  = (const float*)d_in[14]; const float* b1  = (const float*)d_in[15];
  const float* w2  = (const float*)d_in[16]; const float* b2  = (const float*)d_in[17];
  const float* pwq = (const float*)d_in[18]; const float* pbq = (const float*)d_in[19];
  const float* pwk = (const float*)d_in[20]; const float* pbk = (const float*)d_in[21];
  const float* pwv = (const float*)d_in[22]; const float* pbv = (const float*)d_in[23];
  const float* pwo = (const float*)d_in[24]; const float* pbo = (const float*)d_in[25];
  const float* png = (const float*)d_in[26]; const float* pnb = (const float*)d_in[27];
  const float* tng = (const float*)d_in[28]; const float* tnb = (const float*)d_in[29];
  const float* pjw = (const float*)d_in[30]; const float* pjb = (const float*)d_in[31];
  const float* ong = (const float*)d_in[32]; const float* onb = (const float*)d_in[33];
  float* out = (float*)d_out;

  char* p = (char*)d_ws;
  auto alloc = [&](size_t n) { void* r = (void*)p; p += (n + 255) & ~(size_t)255; return r; };

  // weights (bf16, transposed)
  unsigned short* wqkvt = (unsigned short*)alloc((size_t)3 * HID * HID * 2);  // 2304 x 768
  unsigned short* wot   = (unsigned short*)alloc((size_t)HID * HID * 2);
  unsigned short* w1t   = (unsigned short*)alloc((size_t)FFND * HID * 2);
  unsigned short* w2t   = (unsigned short*)alloc((size_t)HID * FFND * 2);
  unsigned short* pqkvt = (unsigned short*)alloc((size_t)3 * HID * HID * 2);
  unsigned short* pwot  = (unsigned short*)alloc((size_t)HID * 2 * HID * 2);
  unsigned short* pjwt  = (unsigned short*)alloc((size_t)EOUTD * HID * 2);
  float*          qkvbias = (float*)alloc((size_t)3 * HID * 4);
  float*          pqkvbias= (float*)alloc((size_t)3 * HID * 4);
  // activations
  unsigned short* bfA   = (unsigned short*)alloc((size_t)TOK * HID * 2);      // h1 -> h -> x3
  unsigned short* QKVb  = (unsigned short*)alloc((size_t)TOK * 3 * HID * 2);  // 65536 x 2304
  unsigned short* bfB   = (unsigned short*)alloc((size_t)TOK * HID * 2);      // attn -> ffn-hidden chunk
  unsigned short* x2b   = (unsigned short*)alloc((size_t)TOK * HID * 2);      // x2 (bf16)
  unsigned short* fusedb= (unsigned short*)alloc((size_t)BATCH * 2 * HID * 2);
  float*          qresb = (float*)alloc((size_t)BATCH * HID * 4);
  float*          preln = (float*)alloc((size_t)BATCH * HID * 4);
  unsigned short* pooledb=(unsigned short*)alloc((size_t)BATCH * HID * 2);
  float*          news  = (float*)alloc((size_t)BATCH * EOUTD * 4);
  (void)ws_size; (void)in_sizes; (void)n_in; (void)out_size;

  // weight prep
  tcast_k<<<dim3(HID/32,  HID/32),  256, 0, stream>>>(wq,  wqkvt,                 HID, HID);
  tcast_k<<<dim3(HID/32,  HID/32),  256, 0, stream>>>(wk,  wqkvt + (size_t)HID*HID,   HID, HID);
  tcast_k<<<dim3(HID/32,  HID/32),  256, 0, stream>>>(wv,  wqkvt + (size_t)2*HID*HID, HID, HID);
  tcast_k<<<dim3(HID/32,  HID/32),  256, 0, stream>>>(wo,  wot,  HID,  HID);
  tcast_k<<<dim3(FFND/32, HID/32),  256, 0, stream>>>(w1,  w1t,  HID,  FFND);
  tcast_k<<<dim3(HID/32,  FFND/32), 256, 0, stream>>>(w2,  w2t,  FFND, HID);
  tcast_k<<<dim3(HID/32,  HID/32),  256, 0, stream>>>(pwq, pqkvt,                 HID, HID);
  tcast_k<<<dim3(HID/32,  HID/32),  256, 0, stream>>>(pwk, pqkvt + (size_t)HID*HID,   HID, HID);
  tcast_k<<<dim3(HID/32,  HID/32),  256, 0, stream>>>(pwv, pqkvt + (size_t)2*HID*HID, HID, HID);
  tcast_k<<<dim3(HID/32,  (2*HID)/32), 256, 0, stream>>>(pwo, pwot, 2*HID, HID);
  tcast_k<<<dim3(EOUTD/32, HID/32), 256, 0, stream>>>(pjw, pjwt, HID,  EOUTD);
  cat3_k<<<9, 256, 0, stream>>>(bq,  bk,  bv,  qkvbias);
  cat3_k<<<9, 256, 0, stream>>>(pbq, pbk, pbv, pqkvbias);

  // LN1
  ln768_k<<<TOK, 256, 0, stream>>>(x, n1g, n1b, bfA);

  // fused QKV GEMM: 65536x2304, K=768
  gemm_k<EPI_OUTB><<<dim3(3*HID/128, TOK/128), 256, 0, stream>>>(
      bfA, wqkvt, qkvbias, nullptr, nullptr, nullptr, QKVb, TOK, 3*HID, HID);

  // fastformer attention -> bfB (stride 768)
  fastattn2_k<false><<<BATCH * NHEAD / 4, 256, 0, stream>>>(
      QKVb, QKVb + HID, QKVb + 2*HID, 3*HID, mask, bfB, nullptr, nullptr);

  // wo proj + f32 resid x -> x2 (bf16)
  gemm_k<EPI_OUTB | EPI_RESF><<<dim3(HID/128, TOK/128), 256, 0, stream>>>(
      bfB, wot, bo, x, nullptr, nullptr, x2b, TOK, HID, HID);

  // LN2 (bf16 in)
  ln768b_k<<<TOK, 256, 0, stream>>>(x2b, n2g, n2b, bfA);

  // FFN in 4 row-chunks of 16384 (hidden reuses bfB)
  for (int c = 0; c < 4; c++) {
    const size_t ro = (size_t)c * 16384;
    gemm_k<EPI_OUTB | EPI_GELU><<<dim3(FFND/128, 16384/128), 256, 0, stream>>>(
        bfA + ro * HID, w1t, b1, nullptr, nullptr, nullptr, bfB, 16384, FFND, HID);
    gemm_k<EPI_OUTB | EPI_RESB><<<dim3(HID/128, 16384/128), 256, 0, stream>>>(
        bfB, w2t, b2, nullptr, x2b + ro * HID, nullptr, bfA + ro * HID, 16384, HID, FFND);
  }
  // bfA = x3 (bf16)

  // fused pool QKV GEMM
  gemm_k<EPI_OUTB><<<dim3(3*HID/128, TOK/128), 256, 0, stream>>>(
      bfA, pqkvt, pqkvbias, nullptr, nullptr, nullptr, QKVb, TOK, 3*HID, HID);

  // pooling core
  fastattn2_k<true><<<BATCH * NHEAD / 4, 256, 0, stream>>>(
      QKVb, QKVb + HID, QKVb + 2*HID, 3*HID, mask, nullptr, fusedb, qresb);

  // pool out proj (+qres) -> preln f32
  gemm_k<EPI_OUTF | EPI_RESF><<<dim3(HID/128, BATCH/128), 256, 0, stream>>>(
      fusedb, pwot, pbo, qresb, nullptr, preln, nullptr, BATCH, HID, 2*HID);

  // double LN -> pooled bf16
  ln2x_k<<<BATCH, 256, 0, stream>>>(preln, png, pnb, tng, tnb, pooledb);

  // proj -> news f32
  gemm_k<EPI_OUTF><<<dim3(EOUTD/128, BATCH/128), 256, 0, stream>>>(
      pooledb, pjwt, pjb, nullptr, nullptr, news, nullptr, BATCH, EOUTD, HID);

  // final LN
  lnf_k<<<BATCH, 256, 0, stream>>>(news, ong, onb, out);
}